// Round 10
// baseline (20.395 us; speedup 1.0000x reference)
//
#include <hip/hip_runtime.h>

// YOLO layer: (64, 30, 76, 76) f32 -> (64, 3*76*76, 10) f32
// out[b, a*G*G + gy*G + gx, :] =
//   [ (sig(x0)+gx)*8, (sig(x1)+gy)*8, exp(x2)*aw, exp(x3)*ah,
//     x4, x5, sig(x6), sig(x7), sig(x8), sig(x9) ]
// R10: R8 structure (QPT=2, 20 KiB LDS, per-wave transpose, no block barrier)
// + NONTEMPORAL global loads/stores via native ext_vector types (the HIP
// float2/float4 classes are rejected by __builtin_nontemporal_*).

#define NB 64
#define NA 3
#define GG 76
#define PLANE (GG * GG)                      // 5776
#define CH 10
#define BLK 256
#define QPT 2
#define PAIRS_PER_BA (PLANE / QPT)           // 2888
#define TOTAL_PAIRS (NB * NA * PAIRS_PER_BA) // 554496
#define GRID_BLKS (TOTAL_PAIRS / BLK)        // 2166 exactly
#define F2_PER_BLK (BLK * CH)                // 2560 f32x2 = 20 KiB
#define F4_PER_BLK (F2_PER_BLK / 2)          // 1280 f32x4
#define F4_PER_WAVE (64 * CH / 2)            // 320 f32x4 per wave slice
#define STRIDE_F 8.0f                        // 608 / 76

typedef float f32x2 __attribute__((ext_vector_type(2)));
typedef float f32x4 __attribute__((ext_vector_type(4)));

__device__ __forceinline__ float sigf(float v) {
    return 1.0f / (1.0f + __expf(-v));
}

__global__ __launch_bounds__(BLK, 8) void yolo_kernel(const float* __restrict__ x,
                                                      const float* __restrict__ anchors,
                                                      float* __restrict__ out) {
    __shared__ f32x2 lds2[F2_PER_BLK];       // output-linear; wave w owns [640w, 640w+640)

    const int t  = threadIdx.x;
    const int w  = t >> 6;                   // wave id in block
    const int l  = t & 63;                   // lane id
    const int q  = blockIdx.x * BLK + t;     // global cell-pair index
    const int ba = q / PAIRS_PER_BA;
    const int ps = q - ba * PAIRS_PER_BA;
    const int s  = ps * QPT;                 // even; gx even, no row wrap
    const int gy = s / GG;
    const int gx = s - gy * GG;
    const int a  = ba % NA;

    const f32x2* __restrict__ xin =
        reinterpret_cast<const f32x2*>(x + (size_t)ba * (CH * PLANE)) + ps;
    const float aw = anchors[a * 4 + 0];
    const float ah = anchors[a * 4 + 1];
    const float fgy = (float)gy;

    // Thread t owns output dwords [20t, 20t+20): cell0 ch0-9, cell1 ch0-9.
    // lds2 base = 10t; cell0 pair k at base+k, cell1 pair k at base+5+k.
    // All 20 dwords lie inside wave w's slice (dwords [1280w, 1280w+1280)).
    const int base = CH * t;

    f32x2 v0 = __builtin_nontemporal_load(xin + 0 * (PLANE / 2));
    f32x2 v1 = __builtin_nontemporal_load(xin + 1 * (PLANE / 2));
    lds2[base + 0] = (f32x2){(sigf(v0.x) + (float)gx) * STRIDE_F,
                             (sigf(v1.x) + fgy) * STRIDE_F};
    lds2[base + 5] = (f32x2){(sigf(v0.y) + (float)(gx + 1)) * STRIDE_F,
                             (sigf(v1.y) + fgy) * STRIDE_F};

    f32x2 v2 = __builtin_nontemporal_load(xin + 2 * (PLANE / 2));
    f32x2 v3 = __builtin_nontemporal_load(xin + 3 * (PLANE / 2));
    lds2[base + 1] = (f32x2){__expf(v2.x) * aw, __expf(v3.x) * ah};
    lds2[base + 6] = (f32x2){__expf(v2.y) * aw, __expf(v3.y) * ah};

    f32x2 v4 = __builtin_nontemporal_load(xin + 4 * (PLANE / 2));
    f32x2 v5 = __builtin_nontemporal_load(xin + 5 * (PLANE / 2));
    lds2[base + 2] = (f32x2){v4.x, v5.x};
    lds2[base + 7] = (f32x2){v4.y, v5.y};

    f32x2 v6 = __builtin_nontemporal_load(xin + 6 * (PLANE / 2));
    f32x2 v7 = __builtin_nontemporal_load(xin + 7 * (PLANE / 2));
    lds2[base + 3] = (f32x2){sigf(v6.x), sigf(v7.x)};
    lds2[base + 8] = (f32x2){sigf(v6.y), sigf(v7.y)};

    f32x2 v8 = __builtin_nontemporal_load(xin + 8 * (PLANE / 2));
    f32x2 v9 = __builtin_nontemporal_load(xin + 9 * (PLANE / 2));
    lds2[base + 4] = (f32x2){sigf(v8.x), sigf(v9.x)};
    lds2[base + 9] = (f32x2){sigf(v8.y), sigf(v9.y)};

    // Wave-internal ordering only: DS ops from one wave execute in order;
    // the fences stop compiler reordering across the type-pun, and the
    // explicit lgkmcnt(0) guarantees LDS write completion before readback.
    __builtin_amdgcn_wave_barrier();
    asm volatile("s_waitcnt lgkmcnt(0)" ::: "memory");
    __builtin_amdgcn_wave_barrier();

    // Wave w's output region is contiguous: 320 f32x4, 5 per lane.
    const f32x4* __restrict__ lds4 = reinterpret_cast<const f32x4*>(lds2);
    f32x4* __restrict__ out4 =
        reinterpret_cast<f32x4*>(out) + (size_t)blockIdx.x * F4_PER_BLK
        + w * F4_PER_WAVE;
#pragma unroll
    for (int j = 0; j < 5; ++j) {
        f32x4 val = lds4[w * F4_PER_WAVE + 64 * j + l];
        __builtin_nontemporal_store(val, out4 + 64 * j + l);
    }
}

extern "C" void kernel_launch(void* const* d_in, const int* in_sizes, int n_in,
                              void* d_out, int out_size, void* d_ws, size_t ws_size,
                              hipStream_t stream) {
    const float* x       = (const float*)d_in[0];
    const float* anchors = (const float*)d_in[1];
    float* out           = (float*)d_out;

    yolo_kernel<<<GRID_BLKS, BLK, 0, stream>>>(x, anchors, out);
}

// Round 11
// 18.856 us; speedup vs baseline: 1.0816x; 1.0816x over previous
//
#include <hip/hip_runtime.h>

// YOLO layer: (64, 30, 76, 76) f32 -> (64, 3*76*76, 10) f32
// out[b, a*G*G + gy*G + gx, :] =
//   [ (sig(x0)+gx)*8, (sig(x1)+gy)*8, exp(x2)*aw, exp(x3)*ah,
//     x4, x5, sig(x6), sig(x7), sig(x8), sig(x9) ]
// R11 = R7 revert (best measured: 18.85 us). QPT=2 (float2 loads), 20 KiB
// LDS/block -> 8 blocks/CU, channel-pair interleaved LDS staging (<=2-way
// bank alias = free), fully-coalesced float4 readback + global store.
// Tested and rejected: scattered float2 stores (R5, 22.5us), 40KiB LDS /
// 4 blocks/CU (R6, 19.3us), wave-fence instead of barrier (R8, 18.98us ~
// noise), nontemporal ld/st (R10, 20.4us — L3 allocation HELPS here).

#define NB 64
#define NA 3
#define GG 76
#define PLANE (GG * GG)                      // 5776
#define CH 10
#define BLK 256
#define QPT 2
#define PAIRS_PER_BA (PLANE / QPT)           // 2888
#define TOTAL_PAIRS (NB * NA * PAIRS_PER_BA) // 554496
#define GRID_BLKS (TOTAL_PAIRS / BLK)        // 2166 exactly
#define F2_PER_BLK (BLK * CH)                // 2560 float2 = 20 KiB
#define F4_PER_BLK (F2_PER_BLK / 2)          // 1280 float4
#define STRIDE_F 8.0f                        // 608 / 76

__device__ __forceinline__ float sigf(float v) {
    return 1.0f / (1.0f + __expf(-v));
}

__global__ __launch_bounds__(BLK, 8) void yolo_kernel(const float* __restrict__ x,
                                                      const float* __restrict__ anchors,
                                                      float* __restrict__ out) {
    __shared__ float2 lds2[F2_PER_BLK];      // output-linear for this block

    const int t  = threadIdx.x;
    const int q  = blockIdx.x * BLK + t;     // global cell-pair index
    const int ba = q / PAIRS_PER_BA;
    const int ps = q - ba * PAIRS_PER_BA;
    const int s  = ps * QPT;                 // even; gx even, no row wrap
    const int gy = s / GG;
    const int gx = s - gy * GG;
    const int a  = ba % NA;

    const float2* __restrict__ xin =
        reinterpret_cast<const float2*>(x + (size_t)ba * (CH * PLANE)) + ps;
    const float aw = anchors[a * 4 + 0];
    const float ah = anchors[a * 4 + 1];
    const float fgy = (float)gy;

    // Thread t owns output dwords [20t, 20t+20): cell0 ch0-9, cell1 ch0-9.
    // lds2 index base = 10t; cell0 pair k at base+k, cell1 pair k at base+5+k.
    const int base = CH * t;

    float2 v0 = xin[0 * (PLANE / 2)];
    float2 v1 = xin[1 * (PLANE / 2)];
    lds2[base + 0] = make_float2((sigf(v0.x) + (float)gx) * STRIDE_F,
                                 (sigf(v1.x) + fgy) * STRIDE_F);
    lds2[base + 5] = make_float2((sigf(v0.y) + (float)(gx + 1)) * STRIDE_F,
                                 (sigf(v1.y) + fgy) * STRIDE_F);

    float2 v2 = xin[2 * (PLANE / 2)];
    float2 v3 = xin[3 * (PLANE / 2)];
    lds2[base + 1] = make_float2(__expf(v2.x) * aw, __expf(v3.x) * ah);
    lds2[base + 6] = make_float2(__expf(v2.y) * aw, __expf(v3.y) * ah);

    float2 v4 = xin[4 * (PLANE / 2)];
    float2 v5 = xin[5 * (PLANE / 2)];
    lds2[base + 2] = make_float2(v4.x, v5.x);
    lds2[base + 7] = make_float2(v4.y, v5.y);

    float2 v6 = xin[6 * (PLANE / 2)];
    float2 v7 = xin[7 * (PLANE / 2)];
    lds2[base + 3] = make_float2(sigf(v6.x), sigf(v7.x));
    lds2[base + 8] = make_float2(sigf(v6.y), sigf(v7.y));

    float2 v8 = xin[8 * (PLANE / 2)];
    float2 v9 = xin[9 * (PLANE / 2)];
    lds2[base + 4] = make_float2(sigf(v8.x), sigf(v9.x));
    lds2[base + 9] = make_float2(sigf(v8.y), sigf(v9.y));

    __syncthreads();

    // Block's output region is contiguous: 1280 float4, 5 per thread.
    const float4* __restrict__ lds4 = reinterpret_cast<const float4*>(lds2);
    float4* __restrict__ out4 =
        reinterpret_cast<float4*>(out) + (size_t)blockIdx.x * F4_PER_BLK;
#pragma unroll
    for (int j = 0; j < 5; ++j) out4[BLK * j + t] = lds4[BLK * j + t];
}

extern "C" void kernel_launch(void* const* d_in, const int* in_sizes, int n_in,
                              void* d_out, int out_size, void* d_ws, size_t ws_size,
                              hipStream_t stream) {
    const float* x       = (const float*)d_in[0];
    const float* anchors = (const float*)d_in[1];
    float* out           = (float*)d_out;

    yolo_kernel<<<GRID_BLKS, BLK, 0, stream>>>(x, anchors, out);
}